// Round 12
// baseline (437.122 us; speedup 1.0000x reference)
//
#include <hip/hip_runtime.h>

#define N_TOT 10000
#define CLS_P 1000
#define NC 10
#define D 1024

#define TK 64             // tile dim (single-wave block: 64x64 tile)
#define DELTA 1.35e-5f
#define INV_SCALE2 4.8828125e-4f   // 2 / 4096  (Xh stores 64*x; acc = 4096*dot)
#define ESC_LOC 128
#define KCHUNKS (D / 32)
#define NT64 ((N_TOT + TK - 1) / TK)   // 157

typedef _Float16 f16x8 __attribute__((ext_vector_type(8)));
typedef float f32x4 __attribute__((ext_vector_type(4)));
typedef const __attribute__((address_space(1))) unsigned int* gptr_t;
typedef __attribute__((address_space(3))) unsigned int* lptr_t;

// ---------------- zero output ----------------
__global__ void zero_kernel(int* __restrict__ out, int n) {
    int i = blockIdx.x * blockDim.x + threadIdx.x;
    if (i < n) out[i] = 0;
}

// ---------------- gather + fp16(64x) + fp64 norms ----------------
__global__ void prep_kernel(const float* __restrict__ feats, const int* __restrict__ ids,
                            unsigned short* __restrict__ Xh,
                            double* __restrict__ sqd, float* __restrict__ sqf) {
    int row = blockIdx.x;
    int id = ids[row];
    const float4* rp = (const float4*)(feats + (size_t)id * D);
    float4 v = rp[threadIdx.x];  // 256 threads * 4 = 1024
    float f[4] = {v.x, v.y, v.z, v.w};
    ushort4 hv;
    unsigned short* hp = &hv.x;
    double s = 0.0;
    #pragma unroll
    for (int e = 0; e < 4; e++) {
        s += (double)f[e] * f[e];
        union { _Float16 h; unsigned short u; } cv;
        cv.h = (_Float16)(f[e] * 64.0f);   // RNE; x64 avoids fp16 denormals
        hp[e] = cv.u;
    }
    *(ushort4*)(Xh + (size_t)row * D + threadIdx.x * 4) = hv;

    #pragma unroll
    for (int off = 32; off > 0; off >>= 1)
        s += __shfl_down(s, off, 64);
    __shared__ double wsum[4];
    int lane = threadIdx.x & 63, wv = threadIdx.x >> 6;
    if (lane == 0) wsum[wv] = s;
    __syncthreads();
    if (threadIdx.x == 0) {
        double t = wsum[0] + wsum[1] + wsum[2] + wsum[3];
        sqd[row] = t;
        sqf[row] = (float)t;
    }
}

// ---------------- fp16 MFMA pairwise count, 64x64 tile per single wave ----------------
// No __syncthreads anywhere in the hot loop: LDS is wave-private; pipeline paced by vmcnt.
// Escalation (borderline fp64 recheck) fused in-block.
__launch_bounds__(64)
__global__ void count_kernel(const unsigned short* __restrict__ Xh,
                             const float* __restrict__ sqf,
                             const double* __restrict__ sqd,
                             const float* __restrict__ feats,
                             const int* __restrict__ ids,
                             int* __restrict__ counts) {
    // ---- band swizzle: 16 i-tiles per band, j fastest -> L2 locality for A-band ----
    int bid = blockIdx.y * NT64 + blockIdx.x;
    int ti = 0, tj = 0;
    {
        int rem = bid, band = 0;
        while (true) {
            int h = NT64 - band * 16; if (h > 16) h = 16;
            int area = h * NT64;
            if (rem < area) { ti = band * 16 + rem % h; tj = rem / h; break; }
            rem -= area; band++;
        }
    }
    if (tj < ti) return;                 // each unordered pair in exactly one block (j>i mask below)
    const int ib = ti * TK, jb = tj * TK;

    // skip tiles that are entirely same-class
    {
        int ihi = ib + TK - 1; if (ihi > N_TOT - 1) ihi = N_TOT - 1;
        int jhi = jb + TK - 1; if (jhi > N_TOT - 1) jhi = N_TOT - 1;
        int ci0 = ib / CLS_P, ci1 = ihi / CLS_P;
        int cj0 = jb / CLS_P, cj1 = jhi / CLS_P;
        if (ci0 == ci1 && cj0 == cj1 && ci0 == cj0) return;
    }

    // 2 buffers x (A 4KB + B 4KB) = 16 KB; per-buffer: A halves [0,2048), B [2048,4096)
    __shared__ unsigned short S[2 * 4096];
    __shared__ int2 esc_buf[ESC_LOC];
    __shared__ int esc_n;

    const int lane = threadIdx.x;        // 0..63, single wave
    const int quad = lane >> 4, col = lane & 15;

    if (lane == 0) esc_n = 0;            // wave-private LDS: DS ops in order, no barrier needed

    // staging mapping: call c covers rows c*16 + rl0; dest = base + c*512 + lane*8 halves
    const int rl0 = lane >> 2;
    const int slot = lane & 3;
    const int q = (slot - rl0 - (rl0 >> 2)) & 3;   // source k-quarter (conflict-break swizzle)

    const unsigned short* srcA[4];
    const unsigned short* srcB[4];
    #pragma unroll
    for (int c = 0; c < 4; c++) {
        int rA = ib + c * 16 + rl0; if (rA > N_TOT - 1) rA = N_TOT - 1;
        int rB = jb + c * 16 + rl0; if (rB > N_TOT - 1) rB = N_TOT - 1;
        srcA[c] = Xh + (size_t)rA * D + q * 8;
        srcB[c] = Xh + (size_t)rB * D + q * 8;
    }

#define STAGE(KC_, BUFBASE_)                                                     \
    {                                                                            \
        _Pragma("unroll")                                                        \
        for (int c = 0; c < 4; c++)                                              \
            __builtin_amdgcn_global_load_lds(                                    \
                (gptr_t)(srcA[c] + (KC_) * 32),                                  \
                (lptr_t)((BUFBASE_) + c * 512), 16, 0, 0);                       \
        _Pragma("unroll")                                                        \
        for (int c = 0; c < 4; c++)                                              \
            __builtin_amdgcn_global_load_lds(                                    \
                (gptr_t)(srcB[c] + (KC_) * 32),                                  \
                (lptr_t)((BUFBASE_) + 2048 + c * 512), 16, 0, 0);                \
    }

    f32x4 acc[4][4];
    #pragma unroll
    for (int it = 0; it < 4; it++)
        #pragma unroll
        for (int jt = 0; jt < 4; jt++)
            acc[it][jt] = (f32x4){0.f, 0.f, 0.f, 0.f};

    f16x8 ah[4], bh[4];

    STAGE(0, S);
    for (int kc = 0; kc < KCHUNKS; kc++) {
        unsigned short* cur = S + (kc & 1) * 4096;
        unsigned short* nxt = S + ((kc + 1) & 1) * 4096;
        if (kc + 1 < KCHUNKS) {
            STAGE(kc + 1, nxt);
            // retire stage kc (issued last iter, had a full iteration in flight); keep kc+1 flying
            asm volatile("s_waitcnt vmcnt(8)" ::: "memory");
        } else {
            asm volatile("s_waitcnt vmcnt(0)" ::: "memory");
        }
        #pragma unroll
        for (int t = 0; t < 4; t++) {
            int rA = t * 16 + col;
            int sA = (quad + rA + (rA >> 2)) & 3;
            ah[t] = *(const f16x8*)(cur + rA * 32 + sA * 8);
            bh[t] = *(const f16x8*)(cur + 2048 + rA * 32 + sA * 8);
        }
        #pragma unroll
        for (int it = 0; it < 4; it++)
            #pragma unroll
            for (int jt = 0; jt < 4; jt++)
                acc[it][jt] = __builtin_amdgcn_mfma_f32_16x16x32_f16(ah[it], bh[jt], acc[it][jt], 0, 0, 0);
    }

    // ---------------- epilogue: threshold, direct global atomics, LDS escalation ----------------
    const float thr_lo = 0.25f - DELTA;
    const float thr_hi = 0.25f + DELTA;

    float sqj[4];
    int clsj[4], jv[4], jidx[4];
    #pragma unroll
    for (int jt = 0; jt < 4; jt++) {
        int j = jb + jt * 16 + col;
        jidx[jt] = j;
        jv[jt] = (j < N_TOT);
        sqj[jt] = jv[jt] ? sqf[j] : 0.f;
        clsj[jt] = j / CLS_P;
    }

    int cj[4] = {0, 0, 0, 0};

    #pragma unroll
    for (int it = 0; it < 4; it++) {
        #pragma unroll
        for (int r = 0; r < 4; r++) {
            int irow = it * 16 + quad * 4 + r;
            int i = ib + irow;
            bool iv = (i < N_TOT);
            float sqi = iv ? sqf[i] : 0.f;
            int clsi = i / CLS_P;
            int ci = 0;
            #pragma unroll
            for (int jt = 0; jt < 4; jt++) {
                int j = jidx[jt];
                bool ok = iv && jv[jt] && (clsj[jt] != clsi) && (j > i);
                float d2 = sqi + sqj[jt] - acc[it][jt][r] * INV_SCALE2;
                bool in = ok && (d2 < thr_lo);
                bool esc = ok && !in && (d2 < thr_hi);
                ci += in ? 1 : 0;
                cj[jt] += in ? 1 : 0;
                if (esc) {
                    int k = atomicAdd(&esc_n, 1);    // LDS atomic, wave-private
                    if (k < ESC_LOC) {
                        esc_buf[k] = make_int2(i, j);
                    } else {
                        // ~never happens (lambda ~5/tile, cap 128): exact inline fp64 check
                        const float* xi = feats + (size_t)ids[i] * D;
                        const float* xj = feats + (size_t)ids[j] * D;
                        double s = 0.0;
                        for (int kk = 0; kk < D; kk++) s += (double)xi[kk] * xj[kk];
                        if (sqd[i] + sqd[j] - 2.0 * s < 0.25) {
                            atomicAdd(&counts[i], 1);
                            atomicAdd(&counts[j], 1);
                        }
                    }
                }
            }
            ci += __shfl_xor(ci, 1, 64);
            ci += __shfl_xor(ci, 2, 64);
            ci += __shfl_xor(ci, 4, 64);
            ci += __shfl_xor(ci, 8, 64);
            if (col == 0 && ci) atomicAdd(&counts[i], ci);
        }
    }
    #pragma unroll
    for (int jt = 0; jt < 4; jt++) {
        int v = cj[jt];
        v += __shfl_xor(v, 16, 64);
        v += __shfl_xor(v, 32, 64);
        if (quad == 0 && v && jv[jt]) atomicAdd(&counts[jidx[jt]], v);
    }

    // ---------------- fused fp64 escalation: 16 lanes per pair, 4 pairs at a time ----------------
    int n = esc_n; if (n > ESC_LOC) n = ESC_LOC;
    const int sub = lane >> 4, l16 = lane & 15;
    for (int p0 = 0; p0 < n; p0 += 4) {
        int p = p0 + sub;
        bool act = (p < n);
        int2 pr = esc_buf[act ? p : 0];
        const float* xi = feats + (size_t)ids[pr.x] * D;
        const float* xj = feats + (size_t)ids[pr.y] * D;
        double s = 0.0;
        int k0 = l16 * 64;
        #pragma unroll
        for (int k = 0; k < 64; k += 4) {
            float4 a = *(const float4*)(xi + k0 + k);
            float4 b = *(const float4*)(xj + k0 + k);
            s += (double)a.x * b.x + (double)a.y * b.y + (double)a.z * b.z + (double)a.w * b.w;
        }
        s += __shfl_xor(s, 1, 64);
        s += __shfl_xor(s, 2, 64);
        s += __shfl_xor(s, 4, 64);
        s += __shfl_xor(s, 8, 64);
        if (act && l16 == 0) {
            double d2 = sqd[pr.x] + sqd[pr.y] - 2.0 * s;
            if (d2 < 0.25) {
                atomicAdd(&counts[pr.x], 1);
                atomicAdd(&counts[pr.y], 1);
            }
        }
    }
}

// ---------------- stable-argsort selection (one thread per p) ----------------
__global__ void sel_kernel(const int* __restrict__ counts, const int* __restrict__ ids,
                           int* __restrict__ out_ids, int pcb) {
    int c = blockIdx.x;
    __shared__ int lc[CLS_P];
    for (int p = threadIdx.x; p < CLS_P; p += blockDim.x)
        lc[p] = counts[c * CLS_P + p];
    __syncthreads();
    int p = threadIdx.x;
    if (p < CLS_P) {
        int cp = lc[p];
        int rank = 0;
        for (int qq = 0; qq < CLS_P; qq++) {
            int cq = lc[qq];
            rank += (cq < cp) || (cq == cp && qq < p);
        }
        if (rank < pcb)
            out_ids[c * pcb + rank] = ids[c * CLS_P + p];
    }
}

extern "C" void kernel_launch(void* const* d_in, const int* in_sizes, int n_in,
                              void* d_out, int out_size, void* d_ws, size_t ws_size,
                              hipStream_t stream) {
    const float* feats = (const float*)d_in[0];
    const int* ids = (const int*)d_in[1];
    int budget = out_size - N_TOT;
    int pcb = budget / NC;  // 200
    int* out = (int*)d_out;
    int* counts_out = out + NC * pcb;

    char* ws = (char*)d_ws;
    const size_t XH_OFF = 0;
    const size_t SQD_OFF = XH_OFF + (size_t)N_TOT * D * 2;           // 20.48 MB
    const size_t SQF_OFF = SQD_OFF + (size_t)N_TOT * 8;

    unsigned short* Xh = (unsigned short*)(ws + XH_OFF);
    double* sqd = (double*)(ws + SQD_OFF);
    float* sqf = (float*)(ws + SQF_OFF);

    zero_kernel<<<(out_size + 255) / 256, 256, 0, stream>>>(out, out_size);
    prep_kernel<<<N_TOT, 256, 0, stream>>>(feats, ids, Xh, sqd, sqf);
    dim3 grid(NT64, NT64);
    count_kernel<<<grid, 64, 0, stream>>>(Xh, sqf, sqd, feats, ids, counts_out);
    sel_kernel<<<NC, 1024, 0, stream>>>(counts_out, ids, out, pcb);
}

// Round 13
// 341.396 us; speedup vs baseline: 1.2804x; 1.2804x over previous
//
#include <hip/hip_runtime.h>

#define N_TOT 10000
#define CLS_P 1000
#define NC 10
#define D 1024

#define TM 128            // block tile (i and j)
#define DELTA 1.35e-5f
#define INV_SCALE2 4.8828125e-4f   // 2 / 4096  (Xh stores 64*x; acc = 4096*dot)
#define ESC_LOC 256
#define KCHUNKS (D / 32)
#define NTILE ((N_TOT + TM - 1) / TM)   // 79

typedef _Float16 f16x8 __attribute__((ext_vector_type(8)));
typedef float f32x4 __attribute__((ext_vector_type(4)));
typedef const __attribute__((address_space(1))) unsigned int* gptr_t;
typedef __attribute__((address_space(3))) unsigned int* lptr_t;

// ---------------- zero output ----------------
__global__ void zero_kernel(int* __restrict__ out, int n) {
    int i = blockIdx.x * blockDim.x + threadIdx.x;
    if (i < n) out[i] = 0;
}

// ---------------- gather + fp16(64x) + fp64 norms ----------------
__global__ void prep_kernel(const float* __restrict__ feats, const int* __restrict__ ids,
                            unsigned short* __restrict__ Xh,
                            double* __restrict__ sqd, float* __restrict__ sqf) {
    int row = blockIdx.x;
    int id = ids[row];
    const float4* rp = (const float4*)(feats + (size_t)id * D);
    float4 v = rp[threadIdx.x];  // 256 threads * 4 = 1024
    float f[4] = {v.x, v.y, v.z, v.w};
    ushort4 hv;
    unsigned short* hp = &hv.x;
    double s = 0.0;
    #pragma unroll
    for (int e = 0; e < 4; e++) {
        s += (double)f[e] * f[e];
        union { _Float16 h; unsigned short u; } cv;
        cv.h = (_Float16)(f[e] * 64.0f);   // RNE; x64 avoids fp16 denormals
        hp[e] = cv.u;
    }
    *(ushort4*)(Xh + (size_t)row * D + threadIdx.x * 4) = hv;

    #pragma unroll
    for (int off = 32; off > 0; off >>= 1)
        s += __shfl_down(s, off, 64);
    __shared__ double wsum[4];
    int lane = threadIdx.x & 63, wv = threadIdx.x >> 6;
    if (lane == 0) wsum[wv] = s;
    __syncthreads();
    if (threadIdx.x == 0) {
        double t = wsum[0] + wsum[1] + wsum[2] + wsum[3];
        sqd[row] = t;
        sqf[row] = (float)t;
    }
}

// ---------------- fp16 MFMA pairwise count (3-buf async, frag read-ahead, fused fp64 escalation) ----------------
__launch_bounds__(256, 3)
__global__ void count_kernel(const unsigned short* __restrict__ Xh,
                             const float* __restrict__ sqf,
                             const double* __restrict__ sqd,
                             const float* __restrict__ feats,
                             const int* __restrict__ ids,
                             int* __restrict__ counts) {
    // ---- band swizzle: 8 i-tiles per band, j fastest -> L2-local working set ----
    int bid = blockIdx.y * gridDim.x + blockIdx.x;
    int it_t = 0, jt_t = 0;
    {
        int rem = bid, band = 0;
        while (true) {
            int h = NTILE - band * 8; if (h > 8) h = 8;
            int area = h * NTILE;
            if (rem < area) { it_t = band * 8 + rem % h; jt_t = rem / h; break; }
            rem -= area; band++;
        }
    }
    const int ib = it_t * TM, jb = jt_t * TM;
    if (jb < ib) return;  // symmetric: only upper triangle of tiles

    // skip tiles that are entirely same-class
    {
        int ci0 = ib / CLS_P, ci1 = (ib + TM - 1) / CLS_P;
        int cj0 = jb / CLS_P, cj1 = (jb + TM - 1) / CLS_P;
        if (ci0 == ci1 && cj0 == cj1 && ci0 == cj0) return;
    }

    // 3 buffers x (A 8KB + B 8KB) = 48 KB
    __shared__ unsigned short S[3 * 8192];
    __shared__ int cred_i[TM], cred_j[TM];
    __shared__ int esc_n;
    __shared__ int2 esc_buf[ESC_LOC];

    const int tid = threadIdx.x;
    const int lane = tid & 63, w = tid >> 6;
    const int wi = (w & 1) * 64, wj = (w >> 1) * 64;
    const int quad = lane >> 4, col = lane & 15;

    if (tid == 0) esc_n = 0;

    // staging: waves 0,1 -> A (rows of ib); waves 2,3 -> B (rows of jb)
    const int warr = w >> 1;
    const int w01 = w & 1;
    const int rl0 = lane >> 2;      // 0..15 row within 16-row call group
    const int slot = lane & 3;      // dest k-slot
    const int q = (slot - rl0 - (rl0 >> 2)) & 3;   // source k-quarter (swizzle)
    const int rowbase = warr ? jb : ib;

    const unsigned short* src[4];
    #pragma unroll
    for (int b = 0; b < 4; b++) {
        int grow = rowbase + b * 32 + w01 * 16 + rl0;
        if (grow > N_TOT - 1) grow = N_TOT - 1;
        src[b] = Xh + (size_t)grow * D + q * 8;
    }

#define STAGE(KC_, BUFBASE_)                                                     \
    {                                                                            \
        _Pragma("unroll")                                                        \
        for (int b = 0; b < 4; b++) {                                            \
            __builtin_amdgcn_global_load_lds(                                    \
                (gptr_t)(src[b] + (KC_) * 32),                                   \
                (lptr_t)((BUFBASE_) + warr * 4096 + b * 1024 + w01 * 512),       \
                16, 0, 0);                                                       \
        }                                                                        \
    }

#define FRAGS_(AH, BH, BUFBASE_)                                                 \
    {                                                                            \
        _Pragma("unroll")                                                        \
        for (int t = 0; t < 4; t++) {                                            \
            int rA = wi + t * 16 + col;                                          \
            int sA = (quad + rA + (rA >> 2)) & 3;                                \
            AH[t] = *(const f16x8*)((BUFBASE_) + rA * 32 + sA * 8);              \
            int rB = wj + t * 16 + col;                                          \
            int sB = (quad + rB + (rB >> 2)) & 3;                                \
            BH[t] = *(const f16x8*)((BUFBASE_) + 4096 + rB * 32 + sB * 8);       \
        }                                                                        \
    }

#define MFMA16_(AH, BH)                                                          \
    {                                                                            \
        _Pragma("unroll")                                                        \
        for (int it = 0; it < 4; it++)                                           \
            _Pragma("unroll")                                                    \
            for (int jt = 0; jt < 4; jt++)                                       \
                acc[it][jt] = __builtin_amdgcn_mfma_f32_16x16x32_f16(AH[it], BH[jt], acc[it][jt], 0, 0, 0); \
    }

#define WAIT4_BAR asm volatile("s_waitcnt vmcnt(4)\ns_barrier" ::: "memory")
#define WAIT0_BAR asm volatile("s_waitcnt vmcnt(0)\ns_barrier" ::: "memory")

    f32x4 acc[4][4];
    #pragma unroll
    for (int it = 0; it < 4; it++)
        #pragma unroll
        for (int jt = 0; jt < 4; jt++)
            acc[it][jt] = (f32x4){0.f, 0.f, 0.f, 0.f};

    f16x8 ah0[4], bh0[4], ah1[4], bh1[4];   // two named frag sets (phase parity)

    unsigned short* p0 = S;                 // data kc   (cur, already in regs)
    unsigned short* p1 = S + 8192;          // data kc+1 (frags read this phase)
    unsigned short* p2 = S + 16384;         // free -> staging kc+2

    // prologue: stage kc0,kc1; retire kc0 (keep kc1 in flight); preload frags0
    STAGE(0, p0);
    STAGE(1, p1);
    WAIT4_BAR;
    FRAGS_(ah0, bh0, p0);

    for (int kc = 0; kc < KCHUNKS - 2; kc += 2) {
        // ---- phase m=kc (cur set0): stage kc+2, read-ahead frags kc+1 -> set1 ----
        STAGE(kc + 2, p2);
        WAIT4_BAR;                 // retire stage(kc+1) everywhere; gate p2 overwrite
        FRAGS_(ah1, bh1, p1);      // ds_reads overlap MFMA below
        MFMA16_(ah0, bh0);
        { unsigned short* t = p0; p0 = p1; p1 = p2; p2 = t; }

        // ---- phase m=kc+1 (cur set1): stage kc+3, read-ahead frags kc+2 -> set0 ----
        STAGE(kc + 3, p2);
        WAIT4_BAR;
        FRAGS_(ah0, bh0, p1);
        MFMA16_(ah1, bh1);
        { unsigned short* t = p0; p0 = p1; p1 = p2; p2 = t; }
    }
    // tail: phase 30 (cur set0), phase 31 (cur set1)
    WAIT0_BAR;                     // retire stage(31)
    FRAGS_(ah1, bh1, p1);
    MFMA16_(ah0, bh0);
    MFMA16_(ah1, bh1);

    // ---------------- epilogue: threshold + LDS-buffered escalate + symmetric reduce ----------------
    if (tid < TM) { cred_i[tid] = 0; cred_j[tid] = 0; }
    __syncthreads();

    const float thr_lo = 0.25f - DELTA;
    const float thr_hi = 0.25f + DELTA;
    const bool diag = (ib == jb);

    float sqj[4];
    int clsj[4], jv[4], jidx[4];
    #pragma unroll
    for (int jt = 0; jt < 4; jt++) {
        int j = jb + wj + jt * 16 + col;
        jidx[jt] = j;
        jv[jt] = (j < N_TOT);
        sqj[jt] = jv[jt] ? sqf[j] : 0.f;
        clsj[jt] = j / CLS_P;
    }

    int cj[4] = {0, 0, 0, 0};

    #pragma unroll
    for (int it = 0; it < 4; it++) {
        #pragma unroll
        for (int r = 0; r < 4; r++) {
            int irow = wi + it * 16 + quad * 4 + r;
            int i = ib + irow;
            bool iv = (i < N_TOT);
            float sqi = iv ? sqf[i] : 0.f;
            int clsi = i / CLS_P;
            int ci = 0;
            #pragma unroll
            for (int jt = 0; jt < 4; jt++) {
                int j = jidx[jt];
                bool ok = iv && jv[jt] && (clsj[jt] != clsi) && (!diag || j > i);
                float d2 = sqi + sqj[jt] - acc[it][jt][r] * INV_SCALE2;
                bool in = ok && (d2 < thr_lo);
                bool esc = ok && !in && (d2 < thr_hi);
                ci += in ? 1 : 0;
                cj[jt] += in ? 1 : 0;
                if (esc) {
                    int k = atomicAdd(&esc_n, 1);      // LDS atomic: fast
                    if (k < ESC_LOC) {
                        esc_buf[k] = make_int2(i, j);
                    } else {
                        // ~never (avg ~16/block, cap 256): exact inline scalar fp64 check
                        const float* xi = feats + (size_t)ids[i] * D;
                        const float* xj = feats + (size_t)ids[j] * D;
                        double s = 0.0;
                        for (int kk = 0; kk < D; kk++) s += (double)xi[kk] * xj[kk];
                        if (sqd[i] + sqd[j] - 2.0 * s < 0.25) {
                            atomicAdd(&counts[i], 1);
                            atomicAdd(&counts[j], 1);
                        }
                    }
                }
            }
            ci += __shfl_xor(ci, 1, 64);
            ci += __shfl_xor(ci, 2, 64);
            ci += __shfl_xor(ci, 4, 64);
            ci += __shfl_xor(ci, 8, 64);
            if (col == 0 && ci) atomicAdd(&cred_i[irow], ci);
        }
    }
    #pragma unroll
    for (int jt = 0; jt < 4; jt++) {
        int v = cj[jt];
        v += __shfl_xor(v, 16, 64);
        v += __shfl_xor(v, 32, 64);
        if (quad == 0 && v) atomicAdd(&cred_j[wj + jt * 16 + col], v);
    }
    __syncthreads();
    if (tid < TM) {
        int i = ib + tid;
        if (i < N_TOT && cred_i[tid]) atomicAdd(&counts[i], cred_i[tid]);
        int j = jb + tid;
        if (j < N_TOT && cred_j[tid]) atomicAdd(&counts[j], cred_j[tid]);
    }
    __syncthreads();   // esc_buf/esc_n visible to all waves

    // ---------------- fused fp64 escalation: 16 lanes/pair, 16 concurrent pairs ----------------
    int n = esc_n; if (n > ESC_LOC) n = ESC_LOC;
    const int sub = lane >> 4, l16 = lane & 15;
    for (int p = w * 4 + sub; p < n; p += 16) {
        int2 pr = esc_buf[p];
        const float* xi = feats + (size_t)ids[pr.x] * D;
        const float* xj = feats + (size_t)ids[pr.y] * D;
        double s = 0.0;
        int k0 = l16 * 64;
        #pragma unroll
        for (int k = 0; k < 64; k += 4) {
            float4 a = *(const float4*)(xi + k0 + k);
            float4 b = *(const float4*)(xj + k0 + k);
            s += (double)a.x * b.x + (double)a.y * b.y + (double)a.z * b.z + (double)a.w * b.w;
        }
        s += __shfl_xor(s, 1, 64);
        s += __shfl_xor(s, 2, 64);
        s += __shfl_xor(s, 4, 64);
        s += __shfl_xor(s, 8, 64);
        if (l16 == 0) {
            double d2 = sqd[pr.x] + sqd[pr.y] - 2.0 * s;
            if (d2 < 0.25) {
                atomicAdd(&counts[pr.x], 1);
                atomicAdd(&counts[pr.y], 1);
            }
        }
    }
}

// ---------------- stable-argsort selection (one thread per p) ----------------
__global__ void sel_kernel(const int* __restrict__ counts, const int* __restrict__ ids,
                           int* __restrict__ out_ids, int pcb) {
    int c = blockIdx.x;
    __shared__ int lc[CLS_P];
    for (int p = threadIdx.x; p < CLS_P; p += blockDim.x)
        lc[p] = counts[c * CLS_P + p];
    __syncthreads();
    int p = threadIdx.x;
    if (p < CLS_P) {
        int cp = lc[p];
        int rank = 0;
        for (int qq = 0; qq < CLS_P; qq++) {
            int cq = lc[qq];
            rank += (cq < cp) || (cq == cp && qq < p);
        }
        if (rank < pcb)
            out_ids[c * pcb + rank] = ids[c * CLS_P + p];
    }
}

extern "C" void kernel_launch(void* const* d_in, const int* in_sizes, int n_in,
                              void* d_out, int out_size, void* d_ws, size_t ws_size,
                              hipStream_t stream) {
    const float* feats = (const float*)d_in[0];
    const int* ids = (const int*)d_in[1];
    int budget = out_size - N_TOT;
    int pcb = budget / NC;  // 200
    int* out = (int*)d_out;
    int* counts_out = out + NC * pcb;

    char* ws = (char*)d_ws;
    const size_t XH_OFF = 0;
    const size_t SQD_OFF = XH_OFF + (size_t)N_TOT * D * 2;           // 20.48 MB
    const size_t SQF_OFF = SQD_OFF + (size_t)N_TOT * 8;

    unsigned short* Xh = (unsigned short*)(ws + XH_OFF);
    double* sqd = (double*)(ws + SQD_OFF);
    float* sqf = (float*)(ws + SQF_OFF);

    zero_kernel<<<(out_size + 255) / 256, 256, 0, stream>>>(out, out_size);
    prep_kernel<<<N_TOT, 256, 0, stream>>>(feats, ids, Xh, sqd, sqf);
    dim3 grid(NTILE, NTILE);
    count_kernel<<<grid, 256, 0, stream>>>(Xh, sqf, sqd, feats, ids, counts_out);
    sel_kernel<<<NC, 1024, 0, stream>>>(counts_out, ids, out, pcb);
}